// Round 3
// baseline (188.899 us; speedup 1.0000x reference)
//
#include <hip/hip_runtime.h>
#include <math.h>

// B,H,W,K = 8,512,512,8 ; P = 1,200,000 ; npix = 2,097,152
// Collapse: out[pix] = (idx0 < 0) ? (1,1,1) : shaded[idx0]
//   (alphas are binary -> transmittance 0 after first valid fragment; final
//    jnp.where overrides with bg whenever slot-0 is a hole.)
//
// R3 = R2 with compile fix: __builtin_nontemporal_* requires NATIVE clang
// vector types, not HIP_vector_type classes -> use ext_vector_type aliases.

#define AMBIENT  0.3f
#define DIFFUSE  0.7f
#define SPECULAR 0.2f

typedef float  fvec4 __attribute__((ext_vector_type(4)));
typedef int    ivec4 __attribute__((ext_vector_type(4)));
typedef unsigned int uvec4 __attribute__((ext_vector_type(4)));

__device__ __forceinline__ unsigned short f2bf(float f) {
    // round-to-nearest-even; inputs are clipped [0,1], no NaN/Inf
    unsigned int u = __float_as_uint(f);
    u = (u + 0x7FFFu + ((u >> 16) & 1u)) >> 16;
    return (unsigned short)u;
}
__device__ __forceinline__ float bf2f(unsigned short h) {
    return __uint_as_float(((unsigned int)h) << 16);
}

__device__ __forceinline__ void shade_regs(
    float nx, float ny, float nz,
    float fx, float fy, float fz,
    float px, float py, float pz,
    float cx, float cy, float cz,
    float lx, float ly, float lz,
    float& r, float& g, float& b)
{
    const float diffuse = fmaxf(nx*lx + ny*ly + nz*lz, 0.0f);

    float vx = cx - px, vy = cy - py, vz = cz - pz;
    float vn = fmaxf(sqrtf(vx*vx + vy*vy + vz*vz), 1e-12f);
    vx /= vn; vy /= vn; vz /= vn;

    float hx = lx + vx, hy = ly + vy, hz = lz + vz;
    float hn = fmaxf(sqrtf(hx*hx + hy*hy + hz*hz), 1e-12f);
    hx /= hn; hy /= hn; hz /= hn;

    float ndh = fmaxf(nx*hx + ny*hy + nz*hz, 0.0f);
    float s = ndh * ndh;  s = s * s;  s = s * s;  s = s * s;  s = s * s; // ^32
    const float spec = SPECULAR * s;
    const float kd = AMBIENT + DIFFUSE * diffuse;

    r = fminf(fmaxf(fx * kd + spec, 0.0f), 1.0f);
    g = fminf(fmaxf(fy * kd + spec, 0.0f), 1.0f);
    b = fminf(fmaxf(fz * kd + spec, 0.0f), 1.0f);
}

__global__ void __launch_bounds__(256) shade_kernel4(
    const fvec4* __restrict__ pts4,
    const fvec4* __restrict__ feat4,
    const fvec4* __restrict__ nrm4,
    const float* __restrict__ cam_centers,
    const ivec4* __restrict__ cld4,
    const float* __restrict__ light_dir,
    ushort4* __restrict__ shaded,
    int P)
{
    const int t = blockIdx.x * blockDim.x + threadIdx.x;
    const int base = t * 4;
    if (base >= P) return;

    float lx = light_dir[0], ly = light_dir[1], lz = light_dir[2];
    const float ln = fmaxf(sqrtf(lx*lx + ly*ly + lz*lz), 1e-12f);
    lx /= ln; ly /= ln; lz /= ln;

    if (base + 4 <= P) {
        // 4 points: 3 fvec4 per attribute, one ivec4 of cloud ids
        fvec4 p0 = __builtin_nontemporal_load(&pts4[3*t+0]);
        fvec4 p1 = __builtin_nontemporal_load(&pts4[3*t+1]);
        fvec4 p2 = __builtin_nontemporal_load(&pts4[3*t+2]);
        fvec4 n0 = __builtin_nontemporal_load(&nrm4[3*t+0]);
        fvec4 n1 = __builtin_nontemporal_load(&nrm4[3*t+1]);
        fvec4 n2 = __builtin_nontemporal_load(&nrm4[3*t+2]);
        fvec4 f0 = __builtin_nontemporal_load(&feat4[3*t+0]);
        fvec4 f1 = __builtin_nontemporal_load(&feat4[3*t+1]);
        fvec4 f2 = __builtin_nontemporal_load(&feat4[3*t+2]);
        ivec4 c4 = __builtin_nontemporal_load(&cld4[t]);

        float pf[12] = {p0.x,p0.y,p0.z,p0.w, p1.x,p1.y,p1.z,p1.w, p2.x,p2.y,p2.z,p2.w};
        float nf[12] = {n0.x,n0.y,n0.z,n0.w, n1.x,n1.y,n1.z,n1.w, n2.x,n2.y,n2.z,n2.w};
        float ff[12] = {f0.x,f0.y,f0.z,f0.w, f1.x,f1.y,f1.z,f1.w, f2.x,f2.y,f2.z,f2.w};
        int   cc[4]  = {c4.x, c4.y, c4.z, c4.w};

        unsigned int packed[8];
        #pragma unroll
        for (int j = 0; j < 4; ++j) {
            const int c = cc[j];
            float r, g, b;
            shade_regs(nf[3*j], nf[3*j+1], nf[3*j+2],
                       ff[3*j], ff[3*j+1], ff[3*j+2],
                       pf[3*j], pf[3*j+1], pf[3*j+2],
                       cam_centers[3*c+0], cam_centers[3*c+1], cam_centers[3*c+2],
                       lx, ly, lz, r, g, b);
            packed[2*j+0] = (unsigned int)f2bf(r) | ((unsigned int)f2bf(g) << 16);
            packed[2*j+1] = (unsigned int)f2bf(b);
        }
        uvec4* dst = (uvec4*)(shaded + base);     // 32B aligned (base % 4 == 0)
        uvec4 w0 = { packed[0], packed[1], packed[2], packed[3] };
        uvec4 w1 = { packed[4], packed[5], packed[6], packed[7] };
        __builtin_nontemporal_store(w0, &dst[0]);
        __builtin_nontemporal_store(w1, &dst[1]);
    } else {
        const float* points   = (const float*)pts4;
        const float* normals  = (const float*)nrm4;
        const float* features = (const float*)feat4;
        const int*   cloud    = (const int*)cld4;
        for (int i = base; i < P; ++i) {
            const int c = cloud[i];
            float r, g, b;
            shade_regs(normals[3*i], normals[3*i+1], normals[3*i+2],
                       features[3*i], features[3*i+1], features[3*i+2],
                       points[3*i], points[3*i+1], points[3*i+2],
                       cam_centers[3*c+0], cam_centers[3*c+1], cam_centers[3*c+2],
                       lx, ly, lz, r, g, b);
            shaded[i] = make_ushort4(f2bf(r), f2bf(g), f2bf(b), 0);
        }
    }
}

__global__ void __launch_bounds__(256) composite_kernel4(
    const int* __restrict__ idx,
    const ushort4* __restrict__ shaded,
    fvec4* __restrict__ out4,
    int npix, int K)
{
    const int t = blockIdx.x * blockDim.x + threadIdx.x;
    const int base = t * 4;
    if (base >= npix) return;

    if (base + 4 <= npix) {
        int i0[4];
        #pragma unroll
        for (int j = 0; j < 4; ++j)
            i0[j] = __builtin_nontemporal_load(idx + (size_t)(base + j) * K);

        ushort4 s[4];
        #pragma unroll
        for (int j = 0; j < 4; ++j) {
            const int ii = i0[j] < 0 ? 0 : i0[j];
            s[j] = shaded[ii];   // 4 independent gathers in flight
        }

        float rgb[12];
        #pragma unroll
        for (int j = 0; j < 4; ++j) {
            if (i0[j] < 0) {
                rgb[3*j+0] = 1.0f; rgb[3*j+1] = 1.0f; rgb[3*j+2] = 1.0f;
            } else {
                rgb[3*j+0] = bf2f(s[j].x);
                rgb[3*j+1] = bf2f(s[j].y);
                rgb[3*j+2] = bf2f(s[j].z);
            }
        }
        fvec4 o0 = { rgb[0], rgb[1], rgb[2],  rgb[3] };
        fvec4 o1 = { rgb[4], rgb[5], rgb[6],  rgb[7] };
        fvec4 o2 = { rgb[8], rgb[9], rgb[10], rgb[11] };
        __builtin_nontemporal_store(o0, &out4[3*t+0]);
        __builtin_nontemporal_store(o1, &out4[3*t+1]);
        __builtin_nontemporal_store(o2, &out4[3*t+2]);
    } else {
        float* out = (float*)out4;
        for (int p = base; p < npix; ++p) {
            const int ii = idx[(size_t)p * K];
            float r = 1.0f, g = 1.0f, b = 1.0f;
            if (ii >= 0) {
                ushort4 sv = shaded[ii];
                r = bf2f(sv.x); g = bf2f(sv.y); b = bf2f(sv.z);
            }
            out[3*p+0] = r; out[3*p+1] = g; out[3*p+2] = b;
        }
    }
}

// Fallback if d_ws can't hold the shaded buffer: fuse shading into the
// per-pixel pass (re-shades referenced points on the fly).
__global__ void fused_kernel(
    const int* __restrict__ idx,
    const float* __restrict__ points,
    const float* __restrict__ features,
    const float* __restrict__ normals,
    const float* __restrict__ cam_centers,
    const int* __restrict__ cloud_idx,
    const float* __restrict__ light_dir,
    float* __restrict__ out,
    int npix, int K)
{
    const int p = blockIdx.x * blockDim.x + threadIdx.x;
    if (p >= npix) return;

    const int i0 = idx[(long long)p * K];
    float r = 1.0f, g = 1.0f, b = 1.0f;
    if (i0 >= 0) {
        float lx = light_dir[0], ly = light_dir[1], lz = light_dir[2];
        const float ln = fmaxf(sqrtf(lx*lx + ly*ly + lz*lz), 1e-12f);
        lx /= ln; ly /= ln; lz /= ln;
        const int c = cloud_idx[i0];
        shade_regs(normals[3*i0], normals[3*i0+1], normals[3*i0+2],
                   features[3*i0], features[3*i0+1], features[3*i0+2],
                   points[3*i0], points[3*i0+1], points[3*i0+2],
                   cam_centers[3*c+0], cam_centers[3*c+1], cam_centers[3*c+2],
                   lx, ly, lz, r, g, b);
    }
    out[3*p+0] = r;
    out[3*p+1] = g;
    out[3*p+2] = b;
}

extern "C" void kernel_launch(void* const* d_in, const int* in_sizes, int n_in,
                              void* d_out, int out_size, void* d_ws, size_t ws_size,
                              hipStream_t stream)
{
    const int*   idx        = (const int*)  d_in[0];
    const float* points     = (const float*)d_in[1];
    const float* features   = (const float*)d_in[2];
    const float* normals    = (const float*)d_in[3];
    const float* cam        = (const float*)d_in[4];
    const int*   cloud_idx  = (const int*)  d_in[5];
    const float* light_dir  = (const float*)d_in[6];

    const int P    = in_sizes[5];
    const int npix = out_size / 3;
    const int K    = in_sizes[0] / npix;

    const int BS = 256;

    if (ws_size >= (size_t)P * sizeof(ushort4)) {
        ushort4* shaded = (ushort4*)d_ws;
        const int shade_threads = (P + 3) / 4;
        shade_kernel4<<<(shade_threads + BS - 1) / BS, BS, 0, stream>>>(
            (const fvec4*)points, (const fvec4*)features, (const fvec4*)normals,
            cam, (const ivec4*)cloud_idx, light_dir, shaded, P);
        const int comp_threads = (npix + 3) / 4;
        composite_kernel4<<<(comp_threads + BS - 1) / BS, BS, 0, stream>>>(
            idx, shaded, (fvec4*)d_out, npix, K);
    } else {
        fused_kernel<<<(npix + BS - 1) / BS, BS, 0, stream>>>(
            idx, points, features, normals, cam, cloud_idx, light_dir,
            (float*)d_out, npix, K);
    }
}

// Round 4
// 175.110 us; speedup vs baseline: 1.0787x; 1.0787x over previous
//
#include <hip/hip_runtime.h>
#include <math.h>

// B,H,W,K = 8,512,512,8 ; P = 1,200,000 ; npix = 2,097,152
// Collapse: out[pix] = (idx0 < 0) ? (1,1,1) : shaded[idx0]
//   (alphas binary -> transmittance 0 after first valid fragment; final
//    jnp.where overrides with bg whenever slot-0 is a hole.)
//
// R4: drop ALL nontemporal hints (R3 showed nt stores ~1.9x write
// amplification: partial 16B-of-64B lines bypass L2 merging; nt loads broke
// same-line reuse of idx). Keep bf16-packed 8B shaded entries. Raise MLP:
// composite 8 px/thread (8 idx loads = four full 64B lines/lane, 8
// independent gathers), shade 4 pts/thread plain vector loads.

#define AMBIENT  0.3f
#define DIFFUSE  0.7f
#define SPECULAR 0.2f

typedef float  fvec4 __attribute__((ext_vector_type(4)));
typedef int    ivec4 __attribute__((ext_vector_type(4)));
typedef unsigned int uvec4 __attribute__((ext_vector_type(4)));

__device__ __forceinline__ unsigned short f2bf(float f) {
    // round-to-nearest-even; inputs clipped [0,1], no NaN/Inf
    unsigned int u = __float_as_uint(f);
    u = (u + 0x7FFFu + ((u >> 16) & 1u)) >> 16;
    return (unsigned short)u;
}
__device__ __forceinline__ float bf2f(unsigned short h) {
    return __uint_as_float(((unsigned int)h) << 16);
}

__device__ __forceinline__ void shade_regs(
    float nx, float ny, float nz,
    float fx, float fy, float fz,
    float px, float py, float pz,
    float cx, float cy, float cz,
    float lx, float ly, float lz,
    float& r, float& g, float& b)
{
    const float diffuse = fmaxf(nx*lx + ny*ly + nz*lz, 0.0f);

    float vx = cx - px, vy = cy - py, vz = cz - pz;
    float vn = fmaxf(sqrtf(vx*vx + vy*vy + vz*vz), 1e-12f);
    vx /= vn; vy /= vn; vz /= vn;

    float hx = lx + vx, hy = ly + vy, hz = lz + vz;
    float hn = fmaxf(sqrtf(hx*hx + hy*hy + hz*hz), 1e-12f);
    hx /= hn; hy /= hn; hz /= hn;

    float ndh = fmaxf(nx*hx + ny*hy + nz*hz, 0.0f);
    float s = ndh * ndh;  s = s * s;  s = s * s;  s = s * s;  s = s * s; // ^32
    const float spec = SPECULAR * s;
    const float kd = AMBIENT + DIFFUSE * diffuse;

    r = fminf(fmaxf(fx * kd + spec, 0.0f), 1.0f);
    g = fminf(fmaxf(fy * kd + spec, 0.0f), 1.0f);
    b = fminf(fmaxf(fz * kd + spec, 0.0f), 1.0f);
}

__global__ void __launch_bounds__(256) shade_kernel4(
    const fvec4* __restrict__ pts4,
    const fvec4* __restrict__ feat4,
    const fvec4* __restrict__ nrm4,
    const float* __restrict__ cam_centers,
    const ivec4* __restrict__ cld4,
    const float* __restrict__ light_dir,
    ushort4* __restrict__ shaded,
    int P)
{
    const int t = blockIdx.x * blockDim.x + threadIdx.x;
    const int base = t * 4;
    if (base >= P) return;

    float lx = light_dir[0], ly = light_dir[1], lz = light_dir[2];
    const float ln = fmaxf(sqrtf(lx*lx + ly*ly + lz*lz), 1e-12f);
    lx /= ln; ly /= ln; lz /= ln;

    if (base + 4 <= P) {
        fvec4 p0 = pts4[3*t+0], p1 = pts4[3*t+1], p2 = pts4[3*t+2];
        fvec4 n0 = nrm4[3*t+0], n1 = nrm4[3*t+1], n2 = nrm4[3*t+2];
        fvec4 f0 = feat4[3*t+0], f1 = feat4[3*t+1], f2 = feat4[3*t+2];
        ivec4 c4 = cld4[t];

        float pf[12] = {p0.x,p0.y,p0.z,p0.w, p1.x,p1.y,p1.z,p1.w, p2.x,p2.y,p2.z,p2.w};
        float nf[12] = {n0.x,n0.y,n0.z,n0.w, n1.x,n1.y,n1.z,n1.w, n2.x,n2.y,n2.z,n2.w};
        float ff[12] = {f0.x,f0.y,f0.z,f0.w, f1.x,f1.y,f1.z,f1.w, f2.x,f2.y,f2.z,f2.w};
        int   cc[4]  = {c4.x, c4.y, c4.z, c4.w};

        unsigned int packed[8];
        #pragma unroll
        for (int j = 0; j < 4; ++j) {
            const int c = cc[j];
            float r, g, b;
            shade_regs(nf[3*j], nf[3*j+1], nf[3*j+2],
                       ff[3*j], ff[3*j+1], ff[3*j+2],
                       pf[3*j], pf[3*j+1], pf[3*j+2],
                       cam_centers[3*c+0], cam_centers[3*c+1], cam_centers[3*c+2],
                       lx, ly, lz, r, g, b);
            packed[2*j+0] = (unsigned int)f2bf(r) | ((unsigned int)f2bf(g) << 16);
            packed[2*j+1] = (unsigned int)f2bf(b);
        }
        uvec4* dst = (uvec4*)(shaded + base);     // 32B aligned (base % 4 == 0)
        uvec4 w0 = { packed[0], packed[1], packed[2], packed[3] };
        uvec4 w1 = { packed[4], packed[5], packed[6], packed[7] };
        dst[0] = w0;
        dst[1] = w1;
    } else {
        const float* points   = (const float*)pts4;
        const float* normals  = (const float*)nrm4;
        const float* features = (const float*)feat4;
        const int*   cloud    = (const int*)cld4;
        for (int i = base; i < P; ++i) {
            const int c = cloud[i];
            float r, g, b;
            shade_regs(normals[3*i], normals[3*i+1], normals[3*i+2],
                       features[3*i], features[3*i+1], features[3*i+2],
                       points[3*i], points[3*i+1], points[3*i+2],
                       cam_centers[3*c+0], cam_centers[3*c+1], cam_centers[3*c+2],
                       lx, ly, lz, r, g, b);
            shaded[i] = make_ushort4(f2bf(r), f2bf(g), f2bf(b), 0);
        }
    }
}

__global__ void __launch_bounds__(256) composite_kernel8(
    const int* __restrict__ idx,
    const ushort4* __restrict__ shaded,
    fvec4* __restrict__ out4,
    int npix, int K)
{
    const int t = blockIdx.x * blockDim.x + threadIdx.x;
    const int base = t * 8;
    if (base >= npix) return;

    if (base + 8 <= npix) {
        int i0[8];
        #pragma unroll
        for (int j = 0; j < 8; ++j)
            i0[j] = idx[(size_t)(base + j) * K];

        ushort4 s[8];
        #pragma unroll
        for (int j = 0; j < 8; ++j) {
            const int ii = i0[j] < 0 ? 0 : i0[j];
            s[j] = shaded[ii];   // 8 independent gathers in flight
        }

        float rgb[24];
        #pragma unroll
        for (int j = 0; j < 8; ++j) {
            if (i0[j] < 0) {
                rgb[3*j+0] = 1.0f; rgb[3*j+1] = 1.0f; rgb[3*j+2] = 1.0f;
            } else {
                rgb[3*j+0] = bf2f(s[j].x);
                rgb[3*j+1] = bf2f(s[j].y);
                rgb[3*j+2] = bf2f(s[j].z);
            }
        }
        #pragma unroll
        for (int j = 0; j < 6; ++j) {
            fvec4 o = { rgb[4*j+0], rgb[4*j+1], rgb[4*j+2], rgb[4*j+3] };
            out4[6*t + j] = o;
        }
    } else {
        float* out = (float*)out4;
        for (int p = base; p < npix; ++p) {
            const int ii = idx[(size_t)p * K];
            float r = 1.0f, g = 1.0f, b = 1.0f;
            if (ii >= 0) {
                ushort4 sv = shaded[ii];
                r = bf2f(sv.x); g = bf2f(sv.y); b = bf2f(sv.z);
            }
            out[3*p+0] = r; out[3*p+1] = g; out[3*p+2] = b;
        }
    }
}

// Fallback if d_ws can't hold the shaded buffer.
__global__ void fused_kernel(
    const int* __restrict__ idx,
    const float* __restrict__ points,
    const float* __restrict__ features,
    const float* __restrict__ normals,
    const float* __restrict__ cam_centers,
    const int* __restrict__ cloud_idx,
    const float* __restrict__ light_dir,
    float* __restrict__ out,
    int npix, int K)
{
    const int p = blockIdx.x * blockDim.x + threadIdx.x;
    if (p >= npix) return;

    const int i0 = idx[(long long)p * K];
    float r = 1.0f, g = 1.0f, b = 1.0f;
    if (i0 >= 0) {
        float lx = light_dir[0], ly = light_dir[1], lz = light_dir[2];
        const float ln = fmaxf(sqrtf(lx*lx + ly*ly + lz*lz), 1e-12f);
        lx /= ln; ly /= ln; lz /= ln;
        const int c = cloud_idx[i0];
        shade_regs(normals[3*i0], normals[3*i0+1], normals[3*i0+2],
                   features[3*i0], features[3*i0+1], features[3*i0+2],
                   points[3*i0], points[3*i0+1], points[3*i0+2],
                   cam_centers[3*c+0], cam_centers[3*c+1], cam_centers[3*c+2],
                   lx, ly, lz, r, g, b);
    }
    out[3*p+0] = r;
    out[3*p+1] = g;
    out[3*p+2] = b;
}

extern "C" void kernel_launch(void* const* d_in, const int* in_sizes, int n_in,
                              void* d_out, int out_size, void* d_ws, size_t ws_size,
                              hipStream_t stream)
{
    const int*   idx        = (const int*)  d_in[0];
    const float* points     = (const float*)d_in[1];
    const float* features   = (const float*)d_in[2];
    const float* normals    = (const float*)d_in[3];
    const float* cam        = (const float*)d_in[4];
    const int*   cloud_idx  = (const int*)  d_in[5];
    const float* light_dir  = (const float*)d_in[6];

    const int P    = in_sizes[5];
    const int npix = out_size / 3;
    const int K    = in_sizes[0] / npix;

    const int BS = 256;

    if (ws_size >= (size_t)P * sizeof(ushort4)) {
        ushort4* shaded = (ushort4*)d_ws;
        const int shade_threads = (P + 3) / 4;
        shade_kernel4<<<(shade_threads + BS - 1) / BS, BS, 0, stream>>>(
            (const fvec4*)points, (const fvec4*)features, (const fvec4*)normals,
            cam, (const ivec4*)cloud_idx, light_dir, shaded, P);
        const int comp_threads = (npix + 7) / 8;
        composite_kernel8<<<(comp_threads + BS - 1) / BS, BS, 0, stream>>>(
            idx, shaded, (fvec4*)d_out, npix, K);
    } else {
        fused_kernel<<<(npix + BS - 1) / BS, BS, 0, stream>>>(
            idx, points, features, normals, cam, cloud_idx, light_dir,
            (float*)d_out, npix, K);
    }
}

// Round 5
// 161.381 us; speedup vs baseline: 1.1705x; 1.0851x over previous
//
#include <hip/hip_runtime.h>
#include <math.h>

// B,H,W,K = 8,512,512,8 ; P = 1,200,000 ; npix = 2,097,152
// Collapse: out[pix] = (idx0 < 0) ? (1,1,1) : shaded[idx0]
//
// R5: gather-footprint attack. shaded entry 8B -> 4B (10-10-10 packed RGB,
// quant err <= 4.9e-4). Footprint 9.6 -> 4.8 MB ~= per-XCD L2 -> gather
// L2-miss bytes ~66 -> ~19 MB (model: hit = 4/4.8). Composite back to the
// best-measured 1 px/thread structure (R1). Shade keeps R4 vectorization,
// writes u32.

#define AMBIENT  0.3f
#define DIFFUSE  0.7f
#define SPECULAR 0.2f

typedef float  fvec4 __attribute__((ext_vector_type(4)));
typedef int    ivec4 __attribute__((ext_vector_type(4)));

__device__ __forceinline__ unsigned int pack101010(float r, float g, float b) {
    // inputs clipped to [0,1]; round-to-nearest
    unsigned int qr = (unsigned int)(r * 1023.0f + 0.5f);
    unsigned int qg = (unsigned int)(g * 1023.0f + 0.5f);
    unsigned int qb = (unsigned int)(b * 1023.0f + 0.5f);
    return qr | (qg << 10) | (qb << 20);
}

__device__ __forceinline__ void unpack101010(unsigned int q, float& r, float& g, float& b) {
    const float s = 1.0f / 1023.0f;
    r = (float)(q & 1023u) * s;
    g = (float)((q >> 10) & 1023u) * s;
    b = (float)((q >> 20) & 1023u) * s;
}

__device__ __forceinline__ void shade_regs(
    float nx, float ny, float nz,
    float fx, float fy, float fz,
    float px, float py, float pz,
    float cx, float cy, float cz,
    float lx, float ly, float lz,
    float& r, float& g, float& b)
{
    const float diffuse = fmaxf(nx*lx + ny*ly + nz*lz, 0.0f);

    float vx = cx - px, vy = cy - py, vz = cz - pz;
    float vn = fmaxf(sqrtf(vx*vx + vy*vy + vz*vz), 1e-12f);
    vx /= vn; vy /= vn; vz /= vn;

    float hx = lx + vx, hy = ly + vy, hz = lz + vz;
    float hn = fmaxf(sqrtf(hx*hx + hy*hy + hz*hz), 1e-12f);
    hx /= hn; hy /= hn; hz /= hn;

    float ndh = fmaxf(nx*hx + ny*hy + nz*hz, 0.0f);
    float s = ndh * ndh;  s = s * s;  s = s * s;  s = s * s;  s = s * s; // ^32
    const float spec = SPECULAR * s;
    const float kd = AMBIENT + DIFFUSE * diffuse;

    r = fminf(fmaxf(fx * kd + spec, 0.0f), 1.0f);
    g = fminf(fmaxf(fy * kd + spec, 0.0f), 1.0f);
    b = fminf(fmaxf(fz * kd + spec, 0.0f), 1.0f);
}

__global__ void __launch_bounds__(256) shade_kernel4(
    const fvec4* __restrict__ pts4,
    const fvec4* __restrict__ feat4,
    const fvec4* __restrict__ nrm4,
    const float* __restrict__ cam_centers,
    const ivec4* __restrict__ cld4,
    const float* __restrict__ light_dir,
    unsigned int* __restrict__ shaded,
    int P)
{
    const int t = blockIdx.x * blockDim.x + threadIdx.x;
    const int base = t * 4;
    if (base >= P) return;

    float lx = light_dir[0], ly = light_dir[1], lz = light_dir[2];
    const float ln = fmaxf(sqrtf(lx*lx + ly*ly + lz*lz), 1e-12f);
    lx /= ln; ly /= ln; lz /= ln;

    if (base + 4 <= P) {
        fvec4 p0 = pts4[3*t+0], p1 = pts4[3*t+1], p2 = pts4[3*t+2];
        fvec4 n0 = nrm4[3*t+0], n1 = nrm4[3*t+1], n2 = nrm4[3*t+2];
        fvec4 f0 = feat4[3*t+0], f1 = feat4[3*t+1], f2 = feat4[3*t+2];
        ivec4 c4 = cld4[t];

        float pf[12] = {p0.x,p0.y,p0.z,p0.w, p1.x,p1.y,p1.z,p1.w, p2.x,p2.y,p2.z,p2.w};
        float nf[12] = {n0.x,n0.y,n0.z,n0.w, n1.x,n1.y,n1.z,n1.w, n2.x,n2.y,n2.z,n2.w};
        float ff[12] = {f0.x,f0.y,f0.z,f0.w, f1.x,f1.y,f1.z,f1.w, f2.x,f2.y,f2.z,f2.w};
        int   cc[4]  = {c4.x, c4.y, c4.z, c4.w};

        ivec4 outq;
        #pragma unroll
        for (int j = 0; j < 4; ++j) {
            const int c = cc[j];
            float r, g, b;
            shade_regs(nf[3*j], nf[3*j+1], nf[3*j+2],
                       ff[3*j], ff[3*j+1], ff[3*j+2],
                       pf[3*j], pf[3*j+1], pf[3*j+2],
                       cam_centers[3*c+0], cam_centers[3*c+1], cam_centers[3*c+2],
                       lx, ly, lz, r, g, b);
            outq[j] = (int)pack101010(r, g, b);
        }
        *(ivec4*)(shaded + base) = outq;   // 16B aligned (base % 4 == 0)
    } else {
        const float* points   = (const float*)pts4;
        const float* normals  = (const float*)nrm4;
        const float* features = (const float*)feat4;
        const int*   cloud    = (const int*)cld4;
        for (int i = base; i < P; ++i) {
            const int c = cloud[i];
            float r, g, b;
            shade_regs(normals[3*i], normals[3*i+1], normals[3*i+2],
                       features[3*i], features[3*i+1], features[3*i+2],
                       points[3*i], points[3*i+1], points[3*i+2],
                       cam_centers[3*c+0], cam_centers[3*c+1], cam_centers[3*c+2],
                       lx, ly, lz, r, g, b);
            shaded[i] = pack101010(r, g, b);
        }
    }
}

__global__ void __launch_bounds__(256) composite_kernel(
    const int* __restrict__ idx,
    const unsigned int* __restrict__ shaded,
    float* __restrict__ out,
    int npix, int K)
{
    const int p = blockIdx.x * blockDim.x + threadIdx.x;
    if (p >= npix) return;
    const int i0 = idx[(size_t)p * K];
    float r = 1.0f, g = 1.0f, b = 1.0f;
    if (i0 >= 0) {
        unpack101010(shaded[i0], r, g, b);
    }
    out[3*p+0] = r;
    out[3*p+1] = g;
    out[3*p+2] = b;
}

// Fallback if d_ws can't hold the shaded buffer.
__global__ void fused_kernel(
    const int* __restrict__ idx,
    const float* __restrict__ points,
    const float* __restrict__ features,
    const float* __restrict__ normals,
    const float* __restrict__ cam_centers,
    const int* __restrict__ cloud_idx,
    const float* __restrict__ light_dir,
    float* __restrict__ out,
    int npix, int K)
{
    const int p = blockIdx.x * blockDim.x + threadIdx.x;
    if (p >= npix) return;

    const int i0 = idx[(long long)p * K];
    float r = 1.0f, g = 1.0f, b = 1.0f;
    if (i0 >= 0) {
        float lx = light_dir[0], ly = light_dir[1], lz = light_dir[2];
        const float ln = fmaxf(sqrtf(lx*lx + ly*ly + lz*lz), 1e-12f);
        lx /= ln; ly /= ln; lz /= ln;
        const int c = cloud_idx[i0];
        shade_regs(normals[3*i0], normals[3*i0+1], normals[3*i0+2],
                   features[3*i0], features[3*i0+1], features[3*i0+2],
                   points[3*i0], points[3*i0+1], points[3*i0+2],
                   cam_centers[3*c+0], cam_centers[3*c+1], cam_centers[3*c+2],
                   lx, ly, lz, r, g, b);
    }
    out[3*p+0] = r;
    out[3*p+1] = g;
    out[3*p+2] = b;
}

extern "C" void kernel_launch(void* const* d_in, const int* in_sizes, int n_in,
                              void* d_out, int out_size, void* d_ws, size_t ws_size,
                              hipStream_t stream)
{
    const int*   idx        = (const int*)  d_in[0];
    const float* points     = (const float*)d_in[1];
    const float* features   = (const float*)d_in[2];
    const float* normals    = (const float*)d_in[3];
    const float* cam        = (const float*)d_in[4];
    const int*   cloud_idx  = (const int*)  d_in[5];
    const float* light_dir  = (const float*)d_in[6];

    const int P    = in_sizes[5];
    const int npix = out_size / 3;
    const int K    = in_sizes[0] / npix;

    const int BS = 256;

    if (ws_size >= (size_t)P * sizeof(unsigned int)) {
        unsigned int* shaded = (unsigned int*)d_ws;
        const int shade_threads = (P + 3) / 4;
        shade_kernel4<<<(shade_threads + BS - 1) / BS, BS, 0, stream>>>(
            (const fvec4*)points, (const fvec4*)features, (const fvec4*)normals,
            cam, (const ivec4*)cloud_idx, light_dir, shaded, P);
        composite_kernel<<<(npix + BS - 1) / BS, BS, 0, stream>>>(
            idx, shaded, (float*)d_out, npix, K);
    } else {
        fused_kernel<<<(npix + BS - 1) / BS, BS, 0, stream>>>(
            idx, points, features, normals, cam, cloud_idx, light_dir,
            (float*)d_out, npix, K);
    }
}